// Round 1
// baseline (2775.073 us; speedup 1.0000x reference)
//
#include <hip/hip_runtime.h>
#include <hip/hip_bf16.h>

#define N_NODES 50000
#define N_EDGES 800000
#define IN_CH 1024
#define OUT_CH 256

typedef __attribute__((ext_vector_type(8))) short bf16x8;
typedef __attribute__((ext_vector_type(4))) float f32x4;

__device__ inline unsigned short f2bf(float f) {
  union { float f; unsigned int u; } v; v.f = f;
  unsigned int r = v.u + 0x7fffu + ((v.u >> 16) & 1u);
  return (unsigned short)(r >> 16);
}

// H[m][n] = sum_k X[m][k]*W[n][k] + b[n];  OUT[m][n] = sw[m]*H[m][n]
// grid: (ceil(M/128), 2), block 256 (4 waves, 2x2 of 64x64 per wave)
__global__ __launch_bounds__(256) void gemm_proj(
    const float* __restrict__ X, const float* __restrict__ Wt,
    const float* __restrict__ bias, const float* __restrict__ sw,
    float* __restrict__ H, float* __restrict__ OUT)
{
  // pad row stride to 40 ushort (80B) -> ~2-way bank aliasing on ds_read_b128 (free)
  __shared__ unsigned short lds_a[128][40];
  __shared__ unsigned short lds_b[128][40];

  const int tid  = threadIdx.x;
  const int lane = tid & 63;
  const int w    = tid >> 6;
  const int wr   = w >> 1, wc = w & 1;
  const int gm0  = blockIdx.x * 128;
  const int gn0  = blockIdx.y * 128;

  // staging role: each thread loads 16 fp32 (one half-row of the 32-wide K tile)
  const int srow = tid >> 1;
  const int skh  = (tid & 1) * 16;

  f32x4 acc[4][4];
  #pragma unroll
  for (int i = 0; i < 4; i++)
    #pragma unroll
    for (int j = 0; j < 4; j++) acc[i][j] = (f32x4)0.0f;

  const int  arow_g  = gm0 + srow;
  const bool arow_ok = (arow_g < N_NODES);
  const float* xrow = X  + (size_t)arow_g * IN_CH + skh;
  const float* wrow = Wt + (size_t)(gn0 + srow) * IN_CH + skh;

  for (int k0 = 0; k0 < IN_CH; k0 += 32) {
    __syncthreads();
    // stage A (x tile), fp32 -> bf16 on the fly
    {
      unsigned short t16[16];
      if (arow_ok) {
        const float4* p = (const float4*)(xrow + k0);
        #pragma unroll
        for (int q = 0; q < 4; q++) {
          float4 f = p[q];
          t16[q*4+0] = f2bf(f.x); t16[q*4+1] = f2bf(f.y);
          t16[q*4+2] = f2bf(f.z); t16[q*4+3] = f2bf(f.w);
        }
      } else {
        #pragma unroll
        for (int q = 0; q < 16; q++) t16[q] = 0;
      }
      *(bf16x8*)&lds_a[srow][skh]     = *(bf16x8*)&t16[0];
      *(bf16x8*)&lds_a[srow][skh + 8] = *(bf16x8*)&t16[8];
    }
    // stage B (W tile, already B^T layout: rows are output channels)
    {
      unsigned short t16[16];
      const float4* p = (const float4*)(wrow + k0);
      #pragma unroll
      for (int q = 0; q < 4; q++) {
        float4 f = p[q];
        t16[q*4+0] = f2bf(f.x); t16[q*4+1] = f2bf(f.y);
        t16[q*4+2] = f2bf(f.z); t16[q*4+3] = f2bf(f.w);
      }
      *(bf16x8*)&lds_b[srow][skh]     = *(bf16x8*)&t16[0];
      *(bf16x8*)&lds_b[srow][skh + 8] = *(bf16x8*)&t16[8];
    }
    __syncthreads();

    // fragments: identical load pattern for A and B^T (row = l&15, k-off = (l>>4)*8)
    bf16x8 af[4], bfr[4];
    const int kk = (lane >> 4) * 8;
    #pragma unroll
    for (int i = 0; i < 4; i++)
      af[i] = *(const bf16x8*)&lds_a[wr*64 + i*16 + (lane & 15)][kk];
    #pragma unroll
    for (int j = 0; j < 4; j++)
      bfr[j] = *(const bf16x8*)&lds_b[wc*64 + j*16 + (lane & 15)][kk];

    #pragma unroll
    for (int i = 0; i < 4; i++)
      #pragma unroll
      for (int j = 0; j < 4; j++)
        acc[i][j] = __builtin_amdgcn_mfma_f32_16x16x32_bf16(af[i], bfr[j], acc[i][j], 0, 0, 0);
  }

  // epilogue: C/D layout col = lane&15, row = (lane>>4)*4 + r  (m89/m91 verified)
  #pragma unroll
  for (int i = 0; i < 4; i++) {
    const int grow_base = gm0 + wr*64 + i*16 + ((lane >> 4) << 2);
    #pragma unroll
    for (int r = 0; r < 4; r++) {
      const int grow = grow_base + r;
      if (grow < N_NODES) {
        const float s = sw[grow];
        #pragma unroll
        for (int j = 0; j < 4; j++) {
          const int gcol = gn0 + wc*64 + j*16 + (lane & 15);
          const float hv = acc[i][j][r] + bias[gcol];
          H[(size_t)grow * OUT_CH + gcol]   = hv;
          OUT[(size_t)grow * OUT_CH + gcol] = s * hv;
        }
      }
    }
  }
}

// one wave per edge: lane reads float4 of h[src], 4 atomic adds into out[tar]
__global__ __launch_bounds__(256) void edge_scatter(
    const float* __restrict__ H, const int* __restrict__ src,
    const int* __restrict__ tar, const float* __restrict__ ew,
    float* __restrict__ OUT)
{
  const int gid = blockIdx.x * blockDim.x + threadIdx.x;
  const int e = gid >> 6;
  if (e >= N_EDGES) return;
  const int lane = threadIdx.x & 63;
  const int s = src[e];
  const int t = tar[e];
  const float wgt = ew[e];
  const float4 v = ((const float4*)(H + (size_t)s * OUT_CH))[lane];
  float* op = OUT + (size_t)t * OUT_CH + lane * 4;
  __hip_atomic_fetch_add(op + 0, wgt * v.x, __ATOMIC_RELAXED, __HIP_MEMORY_SCOPE_AGENT);
  __hip_atomic_fetch_add(op + 1, wgt * v.y, __ATOMIC_RELAXED, __HIP_MEMORY_SCOPE_AGENT);
  __hip_atomic_fetch_add(op + 2, wgt * v.z, __ATOMIC_RELAXED, __HIP_MEMORY_SCOPE_AGENT);
  __hip_atomic_fetch_add(op + 3, wgt * v.w, __ATOMIC_RELAXED, __HIP_MEMORY_SCOPE_AGENT);
}

extern "C" void kernel_launch(void* const* d_in, const int* in_sizes, int n_in,
                              void* d_out, int out_size, void* d_ws, size_t ws_size,
                              hipStream_t stream) {
  const float* x   = (const float*)d_in[0];
  const float* W   = (const float*)d_in[1];
  const float* b   = (const float*)d_in[2];
  const int*   src = (const int*)d_in[3];
  const int*   tar = (const int*)d_in[4];
  const float* ew  = (const float*)d_in[5];
  const float* sw  = (const float*)d_in[6];
  float* out = (float*)d_out;
  float* H   = (float*)d_ws;   // 50000*256*4 = 51.2 MB

  dim3 g1((N_NODES + 127) / 128, OUT_CH / 128);
  gemm_proj<<<g1, 256, 0, stream>>>(x, W, b, sw, H, out);

  const long long nthreads = (long long)N_EDGES * 64;
  edge_scatter<<<(int)((nthreads + 255) / 256), 256, 0, stream>>>(H, src, tar, ew, out);
}

// Round 2
// 328.754 us; speedup vs baseline: 8.4412x; 8.4412x over previous
//
#include <hip/hip_runtime.h>
#include <hip/hip_bf16.h>

#define N_NODES 50000
#define N_EDGES 800000
#define IN_CH 1024
#define OUT_CH 256

typedef __attribute__((ext_vector_type(8))) short bf16x8;
typedef __attribute__((ext_vector_type(4))) float f32x4;

__device__ inline unsigned short f2bf(float f) {
  union { float f; unsigned int u; } v; v.f = f;
  unsigned int r = v.u + 0x7fffu + ((v.u >> 16) & 1u);
  return (unsigned short)(r >> 16);
}
__device__ inline float bf2f(unsigned short u) {
  union { unsigned int u; float f; } v; v.u = ((unsigned int)u) << 16;
  return v.f;
}

// H[m][n] = sum_k X[m][k]*W[n][k] + b[n];  Hb = bf16(H); OUT = sw[m]*H
__global__ __launch_bounds__(256) void gemm_proj(
    const float* __restrict__ X, const float* __restrict__ Wt,
    const float* __restrict__ bias, const float* __restrict__ sw,
    unsigned short* __restrict__ Hb, float* __restrict__ OUT)
{
  __shared__ unsigned short lds_a[128][40];
  __shared__ unsigned short lds_b[128][40];

  const int tid  = threadIdx.x;
  const int lane = tid & 63;
  const int w    = tid >> 6;
  const int wr   = w >> 1, wc = w & 1;
  const int gm0  = blockIdx.x * 128;
  const int gn0  = blockIdx.y * 128;

  const int srow = tid >> 1;
  const int skh  = (tid & 1) * 16;

  f32x4 acc[4][4];
  #pragma unroll
  for (int i = 0; i < 4; i++)
    #pragma unroll
    for (int j = 0; j < 4; j++) acc[i][j] = (f32x4)0.0f;

  const int  arow_g  = gm0 + srow;
  const bool arow_ok = (arow_g < N_NODES);
  const float* xrow = X  + (size_t)arow_g * IN_CH + skh;
  const float* wrow = Wt + (size_t)(gn0 + srow) * IN_CH + skh;

  for (int k0 = 0; k0 < IN_CH; k0 += 32) {
    __syncthreads();
    {
      unsigned short t16[16];
      if (arow_ok) {
        const float4* p = (const float4*)(xrow + k0);
        #pragma unroll
        for (int q = 0; q < 4; q++) {
          float4 f = p[q];
          t16[q*4+0] = f2bf(f.x); t16[q*4+1] = f2bf(f.y);
          t16[q*4+2] = f2bf(f.z); t16[q*4+3] = f2bf(f.w);
        }
      } else {
        #pragma unroll
        for (int q = 0; q < 16; q++) t16[q] = 0;
      }
      *(bf16x8*)&lds_a[srow][skh]     = *(bf16x8*)&t16[0];
      *(bf16x8*)&lds_a[srow][skh + 8] = *(bf16x8*)&t16[8];
    }
    {
      unsigned short t16[16];
      const float4* p = (const float4*)(wrow + k0);
      #pragma unroll
      for (int q = 0; q < 4; q++) {
        float4 f = p[q];
        t16[q*4+0] = f2bf(f.x); t16[q*4+1] = f2bf(f.y);
        t16[q*4+2] = f2bf(f.z); t16[q*4+3] = f2bf(f.w);
      }
      *(bf16x8*)&lds_b[srow][skh]     = *(bf16x8*)&t16[0];
      *(bf16x8*)&lds_b[srow][skh + 8] = *(bf16x8*)&t16[8];
    }
    __syncthreads();

    bf16x8 af[4], bfr[4];
    const int kk = (lane >> 4) * 8;
    #pragma unroll
    for (int i = 0; i < 4; i++)
      af[i] = *(const bf16x8*)&lds_a[wr*64 + i*16 + (lane & 15)][kk];
    #pragma unroll
    for (int j = 0; j < 4; j++)
      bfr[j] = *(const bf16x8*)&lds_b[wc*64 + j*16 + (lane & 15)][kk];

    #pragma unroll
    for (int i = 0; i < 4; i++)
      #pragma unroll
      for (int j = 0; j < 4; j++)
        acc[i][j] = __builtin_amdgcn_mfma_f32_16x16x32_bf16(af[i], bfr[j], acc[i][j], 0, 0, 0);
  }

  #pragma unroll
  for (int i = 0; i < 4; i++) {
    const int grow_base = gm0 + wr*64 + i*16 + ((lane >> 4) << 2);
    #pragma unroll
    for (int r = 0; r < 4; r++) {
      const int grow = grow_base + r;
      if (grow < N_NODES) {
        const float s = sw[grow];
        #pragma unroll
        for (int j = 0; j < 4; j++) {
          const int gcol = gn0 + wc*64 + j*16 + (lane & 15);
          const float hv = acc[i][j][r] + bias[gcol];
          Hb[(size_t)grow * OUT_CH + gcol]  = f2bf(hv);
          OUT[(size_t)grow * OUT_CH + gcol] = s * hv;
        }
      }
    }
  }
}

__global__ __launch_bounds__(256) void zero_counts(int* __restrict__ counts) {
  int i = blockIdx.x * blockDim.x + threadIdx.x;
  if (i < N_NODES) counts[i] = 0;
}

__global__ __launch_bounds__(256) void hist_kernel(const int* __restrict__ tar,
                                                   int* __restrict__ counts) {
  int e = blockIdx.x * blockDim.x + threadIdx.x;
  if (e < N_EDGES) atomicAdd(&counts[tar[e]], 1);
}

// single-block exclusive scan of counts -> offsets (and cursor copy)
__global__ __launch_bounds__(1024) void scan_kernel(const int* __restrict__ counts,
                                                    int* __restrict__ offsets,
                                                    int* __restrict__ cursor) {
  __shared__ int wsum[16];
  __shared__ int carry_s;
  const int tid  = threadIdx.x;
  const int lane = tid & 63;
  const int wv   = tid >> 6;
  if (tid == 0) carry_s = 0;
  __syncthreads();
  for (int base = 0; base < N_NODES; base += 1024) {
    const int i = base + tid;
    const int v = (i < N_NODES) ? counts[i] : 0;
    // inclusive wave scan
    int s = v;
    #pragma unroll
    for (int off = 1; off < 64; off <<= 1) {
      int t = __shfl_up(s, off, 64);
      if (lane >= off) s += t;
    }
    if (lane == 63) wsum[wv] = s;
    __syncthreads();
    if (wv == 0 && lane < 16) {
      int wsv = wsum[lane];
      int ss = wsv;
      #pragma unroll
      for (int off = 1; off < 16; off <<= 1) {
        int t = __shfl_up(ss, off, 64);
        if (lane >= off) ss += t;
      }
      wsum[lane] = ss - wsv;  // exclusive prefix of wave sums
    }
    __syncthreads();
    const int excl = carry_s + wsum[wv] + (s - v);
    if (i < N_NODES) { offsets[i] = excl; cursor[i] = excl; }
    __syncthreads();
    if (tid == 1023) carry_s = excl + v;
    __syncthreads();
  }
  if (tid == 0) offsets[N_NODES] = carry_s;
}

__global__ __launch_bounds__(256) void fill_csr(const int* __restrict__ src,
                                                const int* __restrict__ tar,
                                                const float* __restrict__ ew,
                                                int* __restrict__ cursor,
                                                int2* __restrict__ edata) {
  int e = blockIdx.x * blockDim.x + threadIdx.x;
  if (e >= N_EDGES) return;
  const int t = tar[e];
  const int p = atomicAdd(&cursor[t], 1);
  edata[p] = make_int2(src[e], __float_as_int(ew[e]));
}

// one wave per node: register-accumulate its CSR segment, one non-atomic RMW
__global__ __launch_bounds__(256) void node_agg(
    const unsigned short* __restrict__ Hb, const int* __restrict__ offsets,
    const int2* __restrict__ edata, float* __restrict__ OUT)
{
  const int wid = (blockIdx.x * blockDim.x + threadIdx.x) >> 6;
  if (wid >= N_NODES) return;
  const int lane = threadIdx.x & 63;
  const int e0 = offsets[wid];
  const int e1 = offsets[wid + 1];
  if (e0 == e1) return;

  float a0 = 0.f, a1 = 0.f, a2 = 0.f, a3 = 0.f;
  int e = e0;
  for (; e + 1 < e1; e += 2) {
    const int2 d0 = edata[e];
    const int2 d1 = edata[e + 1];
    const float w0 = __int_as_float(d0.y);
    const float w1 = __int_as_float(d1.y);
    const ushort4 h0 = *(const ushort4*)(Hb + (size_t)d0.x * OUT_CH + lane * 4);
    const ushort4 h1 = *(const ushort4*)(Hb + (size_t)d1.x * OUT_CH + lane * 4);
    a0 += w0 * bf2f(h0.x); a1 += w0 * bf2f(h0.y);
    a2 += w0 * bf2f(h0.z); a3 += w0 * bf2f(h0.w);
    a0 += w1 * bf2f(h1.x); a1 += w1 * bf2f(h1.y);
    a2 += w1 * bf2f(h1.z); a3 += w1 * bf2f(h1.w);
  }
  if (e < e1) {
    const int2 d = edata[e];
    const float w = __int_as_float(d.y);
    const ushort4 h = *(const ushort4*)(Hb + (size_t)d.x * OUT_CH + lane * 4);
    a0 += w * bf2f(h.x); a1 += w * bf2f(h.y);
    a2 += w * bf2f(h.z); a3 += w * bf2f(h.w);
  }

  float* op = OUT + (size_t)wid * OUT_CH + lane * 4;
  float4 cur = *(const float4*)op;
  cur.x += a0; cur.y += a1; cur.z += a2; cur.w += a3;
  *(float4*)op = cur;
}

extern "C" void kernel_launch(void* const* d_in, const int* in_sizes, int n_in,
                              void* d_out, int out_size, void* d_ws, size_t ws_size,
                              hipStream_t stream) {
  const float* x   = (const float*)d_in[0];
  const float* W   = (const float*)d_in[1];
  const float* b   = (const float*)d_in[2];
  const int*   src = (const int*)d_in[3];
  const int*   tar = (const int*)d_in[4];
  const float* ew  = (const float*)d_in[5];
  const float* sw  = (const float*)d_in[6];
  float* out = (float*)d_out;

  // ws layout (all 256B-aligned): Hb 25.6MB | counts | offsets | cursor | edata 6.4MB
  char* ws = (char*)d_ws;
  size_t o = 0;
  unsigned short* Hb = (unsigned short*)(ws + o);
  o += (size_t)N_NODES * OUT_CH * 2;        o = (o + 255) & ~(size_t)255;
  int* counts  = (int*)(ws + o); o += (size_t)N_NODES * 4;       o = (o + 255) & ~(size_t)255;
  int* offsets = (int*)(ws + o); o += (size_t)(N_NODES + 1) * 4; o = (o + 255) & ~(size_t)255;
  int* cursor  = (int*)(ws + o); o += (size_t)N_NODES * 4;       o = (o + 255) & ~(size_t)255;
  int2* edata  = (int2*)(ws + o);

  dim3 g1((N_NODES + 127) / 128, OUT_CH / 128);
  gemm_proj<<<g1, 256, 0, stream>>>(x, W, b, sw, Hb, out);

  zero_counts<<<(N_NODES + 255) / 256, 256, 0, stream>>>(counts);
  hist_kernel<<<(N_EDGES + 255) / 256, 256, 0, stream>>>(tar, counts);
  scan_kernel<<<1, 1024, 0, stream>>>(counts, offsets, cursor);
  fill_csr<<<(N_EDGES + 255) / 256, 256, 0, stream>>>(src, tar, ew, cursor, edata);

  const long long nthreads = (long long)N_NODES * 64;
  node_agg<<<(int)((nthreads + 255) / 256), 256, 0, stream>>>(Hb, offsets, edata, out);
}

// Round 3
// 245.307 us; speedup vs baseline: 11.3126x; 1.3402x over previous
//
#include <hip/hip_runtime.h>
#include <hip/hip_bf16.h>

#define N_NODES 50000
#define N_EDGES 800000
#define IN_CH 1024
#define OUT_CH 256
#define NBLK 196  // ceil(N_NODES/256)

typedef __attribute__((ext_vector_type(8))) short bf16x8;
typedef __attribute__((ext_vector_type(4))) float f32x4;

__device__ inline unsigned short f2bf(float f) {
  union { float f; unsigned int u; } v; v.f = f;
  unsigned int r = v.u + 0x7fffu + ((v.u >> 16) & 1u);
  return (unsigned short)(r >> 16);
}
__device__ inline float bf2f(unsigned short u) {
  union { unsigned int u; float f; } v; v.u = ((unsigned int)u) << 16;
  return v.f;
}

// blocks [0,256): convert W fp32 -> bf16 (4 elems/thread)
// blocks [256,452): zero counts
__global__ __launch_bounds__(256) void prep(const float* __restrict__ W,
                                            unsigned short* __restrict__ Wb,
                                            int* __restrict__ counts) {
  const int b = blockIdx.x, t = threadIdx.x;
  if (b < 256) {
    const int i4 = (b * 256 + t) * 4;
    float4 f = *(const float4*)(W + i4);
    *(ushort4*)(Wb + i4) = make_ushort4(f2bf(f.x), f2bf(f.y), f2bf(f.z), f2bf(f.w));
  } else {
    const int i = (b - 256) * 256 + t;
    if (i < N_NODES) counts[i] = 0;
  }
}

// Hb[m][n] = bf16( sum_k X[m][k]*W[n][k] + b[n] )
// grid (391, 2), 256 threads, 128x128 tile, BK=32, double-buffered LDS, T14 split
__global__ __launch_bounds__(256) void gemm_proj(
    const float* __restrict__ X, const unsigned short* __restrict__ Wb,
    const float* __restrict__ bias, unsigned short* __restrict__ Hb)
{
  __shared__ unsigned short lds_a[2][128][32];
  __shared__ unsigned short lds_b[2][128][32];

  const int tid  = threadIdx.x;
  const int lane = tid & 63;
  const int w    = tid >> 6;
  const int wr   = w >> 1, wc = w & 1;
  const int gm0  = blockIdx.x * 128;
  const int gn0  = blockIdx.y * 128;

  // A staging: round r covers rows [r*32, r*32+32); 8 threads/row, 4 fp32 each (coalesced 128B/row)
  const int arow0 = tid >> 3;          // 0..31
  const int acol  = (tid & 7) * 4;     // 0..28
  // B staging: round r covers rows [r*64, r*64+64); 4 threads/row, 8 bf16 each
  const int brow0 = tid >> 2;          // 0..63
  const int bq8   = (tid & 3) * 8;     // 0..24

  f32x4 acc[4][4];
  #pragma unroll
  for (int i = 0; i < 4; i++)
    #pragma unroll
    for (int j = 0; j < 4; j++) acc[i][j] = (f32x4)0.0f;

  float4 av[4];
  bf16x8 bv[2];

#define LOAD_STEP(K0)                                                          \
  {                                                                            \
    _Pragma("unroll")                                                          \
    for (int r = 0; r < 4; r++) {                                              \
      const int grow = gm0 + arow0 + r * 32;                                   \
      av[r] = (grow < N_NODES)                                                 \
                  ? *(const float4*)(X + (size_t)grow * IN_CH + (K0) + acol)   \
                  : make_float4(0.f, 0.f, 0.f, 0.f);                           \
    }                                                                          \
    _Pragma("unroll")                                                          \
    for (int r = 0; r < 2; r++) {                                              \
      const int wrow = gn0 + brow0 + r * 64;                                   \
      bv[r] = *(const bf16x8*)(Wb + (size_t)wrow * IN_CH + (K0) + bq8);        \
    }                                                                          \
  }

#define WRITE_STEP(BUF)                                                        \
  {                                                                            \
    _Pragma("unroll")                                                          \
    for (int r = 0; r < 4; r++)                                                \
      *(ushort4*)&lds_a[BUF][arow0 + r * 32][acol] =                           \
          make_ushort4(f2bf(av[r].x), f2bf(av[r].y), f2bf(av[r].z),            \
                       f2bf(av[r].w));                                         \
    _Pragma("unroll")                                                          \
    for (int r = 0; r < 2; r++)                                                \
      *(bf16x8*)&lds_b[BUF][brow0 + r * 64][bq8] = bv[r];                      \
  }

  LOAD_STEP(0);
  WRITE_STEP(0);
  __syncthreads();

  int buf = 0;
  for (int ks = 0; ks < IN_CH / 32; ks++) {
    if (ks + 1 < IN_CH / 32) LOAD_STEP((ks + 1) * 32);  // issue next loads early (T14)

    bf16x8 af[4], bfr[4];
    const int kq8 = (lane >> 4) * 8;
    #pragma unroll
    for (int i = 0; i < 4; i++)
      af[i] = *(const bf16x8*)&lds_a[buf][wr * 64 + i * 16 + (lane & 15)][kq8];
    #pragma unroll
    for (int j = 0; j < 4; j++)
      bfr[j] = *(const bf16x8*)&lds_b[buf][wc * 64 + j * 16 + (lane & 15)][kq8];

    #pragma unroll
    for (int i = 0; i < 4; i++)
      #pragma unroll
      for (int j = 0; j < 4; j++)
        acc[i][j] = __builtin_amdgcn_mfma_f32_16x16x32_bf16(af[i], bfr[j], acc[i][j], 0, 0, 0);

    if (ks + 1 < IN_CH / 32) WRITE_STEP(buf ^ 1);
    __syncthreads();
    buf ^= 1;
  }
#undef LOAD_STEP
#undef WRITE_STEP

  // epilogue: C/D layout col = lane&15, row = (lane>>4)*4 + r
  #pragma unroll
  for (int i = 0; i < 4; i++) {
    const int grow_base = gm0 + wr * 64 + i * 16 + ((lane >> 4) << 2);
    #pragma unroll
    for (int r = 0; r < 4; r++) {
      const int grow = grow_base + r;
      if (grow < N_NODES) {
        #pragma unroll
        for (int j = 0; j < 4; j++) {
          const int gcol = gn0 + wc * 64 + j * 16 + (lane & 15);
          Hb[(size_t)grow * OUT_CH + gcol] = f2bf(acc[i][j][r] + bias[gcol]);
        }
      }
    }
  }
}

__global__ __launch_bounds__(256) void hist_kernel(const int* __restrict__ tar,
                                                   int* __restrict__ counts) {
  int e = blockIdx.x * blockDim.x + threadIdx.x;
  if (e < N_EDGES) atomicAdd(&counts[tar[e]], 1);
}

// per-block exclusive scan; write local-excl to offsets, block total to blocksum
__global__ __launch_bounds__(256) void scan_block(const int* __restrict__ counts,
                                                  int* __restrict__ offsets,
                                                  int* __restrict__ blocksum) {
  __shared__ int wsum[4];
  const int tid = threadIdx.x, lane = tid & 63, wv = tid >> 6;
  const int i = blockIdx.x * 256 + tid;
  const int v = (i < N_NODES) ? counts[i] : 0;
  int s = v;
  #pragma unroll
  for (int off = 1; off < 64; off <<= 1) {
    int t = __shfl_up(s, off, 64);
    if (lane >= off) s += t;
  }
  if (lane == 63) wsum[wv] = s;
  __syncthreads();
  if (tid == 0) {
    int c = 0;
    #pragma unroll
    for (int k = 0; k < 4; k++) { int t = wsum[k]; wsum[k] = c; c += t; }
  }
  __syncthreads();
  const int excl = wsum[wv] + s - v;
  if (i < N_NODES) offsets[i] = excl;
  if (tid == 255) blocksum[blockIdx.x] = excl + v;
}

// single block: exclusive scan of the 196 block sums; also write offsets[N_NODES]
__global__ __launch_bounds__(256) void scan_sums(int* __restrict__ blocksum,
                                                 int* __restrict__ offsets) {
  __shared__ int wsum[4];
  const int tid = threadIdx.x, lane = tid & 63, wv = tid >> 6;
  const int v = (tid < NBLK) ? blocksum[tid] : 0;
  int s = v;
  #pragma unroll
  for (int off = 1; off < 64; off <<= 1) {
    int t = __shfl_up(s, off, 64);
    if (lane >= off) s += t;
  }
  if (lane == 63) wsum[wv] = s;
  __syncthreads();
  if (tid == 0) {
    int c = 0;
    #pragma unroll
    for (int k = 0; k < 4; k++) { int t = wsum[k]; wsum[k] = c; c += t; }
  }
  __syncthreads();
  const int excl = wsum[wv] + s - v;
  if (tid < NBLK) blocksum[tid] = excl;
  if (tid == 255) offsets[N_NODES] = excl;  // total (v==0 for tid>=NBLK)
}

__global__ __launch_bounds__(256) void finalize_offsets(int* __restrict__ offsets,
                                                        const int* __restrict__ blocksum,
                                                        int* __restrict__ cursor) {
  const int i = blockIdx.x * 256 + threadIdx.x;
  if (i < N_NODES) {
    const int off = offsets[i] + blocksum[i >> 8];
    offsets[i] = off;
    cursor[i] = off;
  }
}

__global__ __launch_bounds__(256) void fill_csr(const int* __restrict__ src,
                                                const int* __restrict__ tar,
                                                const float* __restrict__ ew,
                                                int* __restrict__ cursor,
                                                int2* __restrict__ edata) {
  int e = blockIdx.x * blockDim.x + threadIdx.x;
  if (e >= N_EDGES) return;
  const int t = tar[e];
  const int p = atomicAdd(&cursor[t], 1);
  edata[p] = make_int2(src[e], __float_as_int(ew[e]));
}

// one wave per node: OUT = sw*h_self + sum_e w_e * h_src
// edata prefetched into lanes; (src,w) broadcast via shfl; 4 gathers in flight
__global__ __launch_bounds__(256) void node_agg(
    const unsigned short* __restrict__ Hb, const int* __restrict__ offsets,
    const int2* __restrict__ edata, const float* __restrict__ sw,
    float* __restrict__ OUT)
{
  const int wid = (blockIdx.x * blockDim.x + threadIdx.x) >> 6;
  if (wid >= N_NODES) return;
  const int lane = threadIdx.x & 63;
  const int e0 = offsets[wid];
  const int e1 = offsets[wid + 1];

  float a0 = 0.f, a1 = 0.f, a2 = 0.f, a3 = 0.f;

  for (int base = e0; base < e1; base += 64) {
    const int avail = e1 - base;
    int2 d = make_int2(0, 0);
    if (lane < avail) d = edata[base + lane];
    const int n = (avail < 64) ? avail : 64;
    int j = 0;
    for (; j + 4 <= n; j += 4) {
      const int   s0 = __shfl(d.x, j, 64),     s1 = __shfl(d.x, j + 1, 64);
      const int   s2 = __shfl(d.x, j + 2, 64), s3 = __shfl(d.x, j + 3, 64);
      const float w0 = __int_as_float(__shfl(d.y, j, 64));
      const float w1 = __int_as_float(__shfl(d.y, j + 1, 64));
      const float w2 = __int_as_float(__shfl(d.y, j + 2, 64));
      const float w3 = __int_as_float(__shfl(d.y, j + 3, 64));
      const ushort4 h0 = *(const ushort4*)(Hb + (size_t)s0 * OUT_CH + lane * 4);
      const ushort4 h1 = *(const ushort4*)(Hb + (size_t)s1 * OUT_CH + lane * 4);
      const ushort4 h2 = *(const ushort4*)(Hb + (size_t)s2 * OUT_CH + lane * 4);
      const ushort4 h3 = *(const ushort4*)(Hb + (size_t)s3 * OUT_CH + lane * 4);
      a0 += w0 * bf2f(h0.x) + w1 * bf2f(h1.x) + w2 * bf2f(h2.x) + w3 * bf2f(h3.x);
      a1 += w0 * bf2f(h0.y) + w1 * bf2f(h1.y) + w2 * bf2f(h2.y) + w3 * bf2f(h3.y);
      a2 += w0 * bf2f(h0.z) + w1 * bf2f(h1.z) + w2 * bf2f(h2.z) + w3 * bf2f(h3.z);
      a3 += w0 * bf2f(h0.w) + w1 * bf2f(h1.w) + w2 * bf2f(h2.w) + w3 * bf2f(h3.w);
    }
    for (; j < n; j++) {
      const int   s = __shfl(d.x, j, 64);
      const float wgt = __int_as_float(__shfl(d.y, j, 64));
      const ushort4 h = *(const ushort4*)(Hb + (size_t)s * OUT_CH + lane * 4);
      a0 += wgt * bf2f(h.x); a1 += wgt * bf2f(h.y);
      a2 += wgt * bf2f(h.z); a3 += wgt * bf2f(h.w);
    }
  }

  const float swv = sw[wid];
  const ushort4 hs = *(const ushort4*)(Hb + (size_t)wid * OUT_CH + lane * 4);
  float4 o;
  o.x = a0 + swv * bf2f(hs.x);
  o.y = a1 + swv * bf2f(hs.y);
  o.z = a2 + swv * bf2f(hs.z);
  o.w = a3 + swv * bf2f(hs.w);
  *(float4*)(OUT + (size_t)wid * OUT_CH + lane * 4) = o;
}

extern "C" void kernel_launch(void* const* d_in, const int* in_sizes, int n_in,
                              void* d_out, int out_size, void* d_ws, size_t ws_size,
                              hipStream_t stream) {
  const float* x   = (const float*)d_in[0];
  const float* W   = (const float*)d_in[1];
  const float* b   = (const float*)d_in[2];
  const int*   src = (const int*)d_in[3];
  const int*   tar = (const int*)d_in[4];
  const float* ew  = (const float*)d_in[5];
  const float* sw  = (const float*)d_in[6];
  float* out = (float*)d_out;

  // ws: Wb 0.5MB | Hb 25.6MB | counts | offsets | cursor | blocksum | edata 6.4MB  (~33MB)
  char* ws = (char*)d_ws;
  size_t o = 0;
  unsigned short* Wb = (unsigned short*)(ws + o);
  o += (size_t)OUT_CH * IN_CH * 2;          o = (o + 255) & ~(size_t)255;
  unsigned short* Hb = (unsigned short*)(ws + o);
  o += (size_t)N_NODES * OUT_CH * 2;        o = (o + 255) & ~(size_t)255;
  int* counts   = (int*)(ws + o); o += (size_t)N_NODES * 4;       o = (o + 255) & ~(size_t)255;
  int* offsets  = (int*)(ws + o); o += (size_t)(N_NODES + 1) * 4; o = (o + 255) & ~(size_t)255;
  int* cursor   = (int*)(ws + o); o += (size_t)N_NODES * 4;       o = (o + 255) & ~(size_t)255;
  int* blocksum = (int*)(ws + o); o += (size_t)NBLK * 4;          o = (o + 255) & ~(size_t)255;
  int2* edata   = (int2*)(ws + o);

  prep<<<256 + NBLK, 256, 0, stream>>>(W, Wb, counts);

  dim3 g1((N_NODES + 127) / 128, OUT_CH / 128);
  gemm_proj<<<g1, 256, 0, stream>>>(x, Wb, b, Hb);

  hist_kernel<<<(N_EDGES + 255) / 256, 256, 0, stream>>>(tar, counts);
  scan_block<<<NBLK, 256, 0, stream>>>(counts, offsets, blocksum);
  scan_sums<<<1, 256, 0, stream>>>(blocksum, offsets);
  finalize_offsets<<<NBLK, 256, 0, stream>>>(offsets, blocksum, cursor);
  fill_csr<<<(N_EDGES + 255) / 256, 256, 0, stream>>>(src, tar, ew, cursor, edata);

  const long long nthreads = (long long)N_NODES * 64;
  node_agg<<<(int)((nthreads + 255) / 256), 256, 0, stream>>>(Hb, offsets, edata, sw, out);
}

// Round 4
// 244.032 us; speedup vs baseline: 11.3718x; 1.0052x over previous
//
#include <hip/hip_runtime.h>
#include <hip/hip_bf16.h>

#define N_NODES 50000
#define N_EDGES 800000
#define IN_CH 1024
#define OUT_CH 256
#define NBLK 196  // ceil(N_NODES/256)

typedef __attribute__((ext_vector_type(8))) short bf16x8;
typedef __attribute__((ext_vector_type(4))) float f32x4;

__device__ inline unsigned short f2bf(float f) {
  union { float f; unsigned int u; } v; v.f = f;
  unsigned int r = v.u + 0x7fffu + ((v.u >> 16) & 1u);
  return (unsigned short)(r >> 16);
}
__device__ inline float bf2f(unsigned short u) {
  union { unsigned int u; float f; } v; v.u = ((unsigned int)u) << 16;
  return v.f;
}

// blocks [0,256): convert W fp32 -> bf16; blocks [256,...): histogram of tar
__global__ __launch_bounds__(256) void prep_hist(const float* __restrict__ W,
                                                 unsigned short* __restrict__ Wb,
                                                 const int* __restrict__ tar,
                                                 int* __restrict__ counts) {
  const int b = blockIdx.x, t = threadIdx.x;
  if (b < 256) {
    const int i4 = (b * 256 + t) * 4;
    float4 f = *(const float4*)(W + i4);
    *(ushort4*)(Wb + i4) = make_ushort4(f2bf(f.x), f2bf(f.y), f2bf(f.z), f2bf(f.w));
  } else {
    const int e = (b - 256) * 256 + t;
    if (e < N_EDGES) atomicAdd(&counts[tar[e]], 1);
  }
}

// Hb[m][n] = bf16( sum_k X[m][k]*W[n][k] + b[n] )
// 64x128 tile, BK=32, grid (782,2): ~6.1 blocks/CU. 4 waves (2x2), wave tile 32x64.
// 2-step-deep register prefetch, double-buffered LDS, 1 barrier/step.
__global__ __launch_bounds__(256, 4) void gemm_proj(
    const float* __restrict__ X, const unsigned short* __restrict__ Wb,
    const float* __restrict__ bias, unsigned short* __restrict__ Hb)
{
  __shared__ unsigned short lds_a[2][64][32];    // 8 KB
  __shared__ unsigned short lds_b[2][128][32];   // 16 KB

  const int tid  = threadIdx.x;
  const int lane = tid & 63;
  const int w    = tid >> 6;
  const int wr   = w >> 1, wc = w & 1;
  const int gm0  = blockIdx.x * 64;
  const int gn0  = blockIdx.y * 128;

  // A staging: 64 rows x 32 fp32; 8 thr/row (float4), rows tid>>3 and +32
  const int ar = tid >> 3;         // 0..31
  const int ac = (tid & 7) * 4;    // fp32 col
  // B staging: 128 rows x 32 bf16; 4 thr/row (bf16x8), rows tid>>2 and +64
  const int br = tid >> 2;         // 0..63
  const int bc = (tid & 3) * 8;    // bf16 col

  const int arow0 = gm0 + ar, arow1 = gm0 + ar + 32;
  const bool aok0 = arow0 < N_NODES, aok1 = arow1 < N_NODES;
  const float* xp0 = X + (size_t)arow0 * IN_CH + ac;
  const float* xp1 = X + (size_t)arow1 * IN_CH + ac;
  const unsigned short* wp0 = Wb + (size_t)(gn0 + br) * IN_CH + bc;
  const unsigned short* wp1 = Wb + (size_t)(gn0 + br + 64) * IN_CH + bc;

  f32x4 acc[2][4];
  #pragma unroll
  for (int i = 0; i < 2; i++)
    #pragma unroll
    for (int j = 0; j < 4; j++) acc[i][j] = (f32x4)0.0f;

  float4 avA0, avA1, avB0, avB1;
  bf16x8 bvA0, bvA1, bvB0, bvB1;

#define LOADR(KS, AV0, AV1, BV0, BV1)                                          \
  {                                                                            \
    const int k0_ = (KS) * 32;                                                 \
    AV0 = aok0 ? *(const float4*)(xp0 + k0_) : make_float4(0.f, 0.f, 0.f, 0.f);\
    AV1 = aok1 ? *(const float4*)(xp1 + k0_) : make_float4(0.f, 0.f, 0.f, 0.f);\
    BV0 = *(const bf16x8*)(wp0 + k0_);                                         \
    BV1 = *(const bf16x8*)(wp1 + k0_);                                         \
  }

#define WRITER(BUF, AV0, AV1, BV0, BV1)                                        \
  {                                                                            \
    *(ushort4*)&lds_a[BUF][ar][ac] =                                           \
        make_ushort4(f2bf(AV0.x), f2bf(AV0.y), f2bf(AV0.z), f2bf(AV0.w));      \
    *(ushort4*)&lds_a[BUF][ar + 32][ac] =                                      \
        make_ushort4(f2bf(AV1.x), f2bf(AV1.y), f2bf(AV1.z), f2bf(AV1.w));      \
    *(bf16x8*)&lds_b[BUF][br][bc]      = BV0;                                  \
    *(bf16x8*)&lds_b[BUF][br + 64][bc] = BV1;                                  \
  }

#define COMPUTE(BUF)                                                           \
  {                                                                            \
    const int l15_ = lane & 15;                                                \
    const int kb_  = (lane >> 4) * 8;                                          \
    bf16x8 a0 = *(const bf16x8*)&lds_a[BUF][wr * 32 + l15_][kb_];              \
    bf16x8 a1 = *(const bf16x8*)&lds_a[BUF][wr * 32 + 16 + l15_][kb_];         \
    bf16x8 b0 = *(const bf16x8*)&lds_b[BUF][wc * 64 + l15_][kb_];              \
    bf16x8 b1 = *(const bf16x8*)&lds_b[BUF][wc * 64 + 16 + l15_][kb_];         \
    bf16x8 b2 = *(const bf16x8*)&lds_b[BUF][wc * 64 + 32 + l15_][kb_];         \
    bf16x8 b3 = *(const bf16x8*)&lds_b[BUF][wc * 64 + 48 + l15_][kb_];         \
    acc[0][0] = __builtin_amdgcn_mfma_f32_16x16x32_bf16(a0, b0, acc[0][0], 0, 0, 0); \
    acc[0][1] = __builtin_amdgcn_mfma_f32_16x16x32_bf16(a0, b1, acc[0][1], 0, 0, 0); \
    acc[0][2] = __builtin_amdgcn_mfma_f32_16x16x32_bf16(a0, b2, acc[0][2], 0, 0, 0); \
    acc[0][3] = __builtin_amdgcn_mfma_f32_16x16x32_bf16(a0, b3, acc[0][3], 0, 0, 0); \
    acc[1][0] = __builtin_amdgcn_mfma_f32_16x16x32_bf16(a1, b0, acc[1][0], 0, 0, 0); \
    acc[1][1] = __builtin_amdgcn_mfma_f32_16x16x32_bf16(a1, b1, acc[1][1], 0, 0, 0); \
    acc[1][2] = __builtin_amdgcn_mfma_f32_16x16x32_bf16(a1, b2, acc[1][2], 0, 0, 0); \
    acc[1][3] = __builtin_amdgcn_mfma_f32_16x16x32_bf16(a1, b3, acc[1][3], 0, 0, 0); \
  }

  // prologue: step0 -> buf0 (written), step1 -> regs B
  LOADR(0, avA0, avA1, bvA0, bvA1);
  WRITER(0, avA0, avA1, bvA0, bvA1);
  LOADR(1, avB0, avB1, bvB0, bvB1);
  __syncthreads();

  for (int ks = 0; ks < 32; ks += 2) {
    // even step ks: compute buf0; write step ks+1 (regsB) -> buf1; load ks+2 -> regsA
    if (ks + 2 < 32) LOADR(ks + 2, avA0, avA1, bvA0, bvA1);
    COMPUTE(0);
    WRITER(1, avB0, avB1, bvB0, bvB1);
    __syncthreads();
    // odd step ks+1: compute buf1; write step ks+2 (regsA) -> buf0; load ks+3 -> regsB
    if (ks + 3 < 32) LOADR(ks + 3, avB0, avB1, bvB0, bvB1);
    COMPUTE(1);
    if (ks + 2 < 32) WRITER(0, avA0, avA1, bvA0, bvA1);
    __syncthreads();
  }
#undef LOADR
#undef WRITER
#undef COMPUTE

  // epilogue: C/D layout col = lane&15, row = (lane>>4)*4 + r
  float bj[4];
  #pragma unroll
  for (int j = 0; j < 4; j++)
    bj[j] = bias[gn0 + wc * 64 + j * 16 + (lane & 15)];

  #pragma unroll
  for (int i = 0; i < 2; i++) {
    const int grow_base = gm0 + wr * 32 + i * 16 + ((lane >> 4) << 2);
    #pragma unroll
    for (int r = 0; r < 4; r++) {
      const int grow = grow_base + r;
      if (grow < N_NODES) {
        #pragma unroll
        for (int j = 0; j < 4; j++) {
          const int gcol = gn0 + wc * 64 + j * 16 + (lane & 15);
          Hb[(size_t)grow * OUT_CH + gcol] = f2bf(acc[i][j][r] + bj[j]);
        }
      }
    }
  }
}

// per-block exclusive scan; local-excl to offsets, block total to blocksum
__global__ __launch_bounds__(256) void scan_block(const int* __restrict__ counts,
                                                  int* __restrict__ offsets,
                                                  int* __restrict__ blocksum) {
  __shared__ int wsum[4];
  const int tid = threadIdx.x, lane = tid & 63, wv = tid >> 6;
  const int i = blockIdx.x * 256 + tid;
  const int v = (i < N_NODES) ? counts[i] : 0;
  int s = v;
  #pragma unroll
  for (int off = 1; off < 64; off <<= 1) {
    int t = __shfl_up(s, off, 64);
    if (lane >= off) s += t;
  }
  if (lane == 63) wsum[wv] = s;
  __syncthreads();
  if (tid == 0) {
    int c = 0;
    #pragma unroll
    for (int k = 0; k < 4; k++) { int t = wsum[k]; wsum[k] = c; c += t; }
  }
  __syncthreads();
  const int excl = wsum[wv] + s - v;
  if (i < N_NODES) offsets[i] = excl;
  if (tid == 255) blocksum[blockIdx.x] = excl + v;
}

__global__ __launch_bounds__(256) void scan_sums(int* __restrict__ blocksum,
                                                 int* __restrict__ offsets) {
  __shared__ int wsum[4];
  const int tid = threadIdx.x, lane = tid & 63, wv = tid >> 6;
  const int v = (tid < NBLK) ? blocksum[tid] : 0;
  int s = v;
  #pragma unroll
  for (int off = 1; off < 64; off <<= 1) {
    int t = __shfl_up(s, off, 64);
    if (lane >= off) s += t;
  }
  if (lane == 63) wsum[wv] = s;
  __syncthreads();
  if (tid == 0) {
    int c = 0;
    #pragma unroll
    for (int k = 0; k < 4; k++) { int t = wsum[k]; wsum[k] = c; c += t; }
  }
  __syncthreads();
  const int excl = wsum[wv] + s - v;
  if (tid < NBLK) blocksum[tid] = excl;
  if (tid == 255) offsets[N_NODES] = excl;
}

__global__ __launch_bounds__(256) void finalize_offsets(int* __restrict__ offsets,
                                                        const int* __restrict__ blocksum,
                                                        int* __restrict__ cursor) {
  const int i = blockIdx.x * 256 + threadIdx.x;
  if (i < N_NODES) {
    const int off = offsets[i] + blocksum[i >> 8];
    offsets[i] = off;
    cursor[i] = off;
  }
}

__global__ __launch_bounds__(256) void fill_csr(const int* __restrict__ src,
                                                const int* __restrict__ tar,
                                                const float* __restrict__ ew,
                                                int* __restrict__ cursor,
                                                int2* __restrict__ edata) {
  int e = blockIdx.x * blockDim.x + threadIdx.x;
  if (e >= N_EDGES) return;
  const int t = tar[e];
  const int p = atomicAdd(&cursor[t], 1);
  edata[p] = make_int2(src[e], __float_as_int(ew[e]));
}

// one wave per node: OUT = sw*h_self + sum_e w_e * h_src
__global__ __launch_bounds__(256) void node_agg(
    const unsigned short* __restrict__ Hb, const int* __restrict__ offsets,
    const int2* __restrict__ edata, const float* __restrict__ sw,
    float* __restrict__ OUT)
{
  const int wid = (blockIdx.x * blockDim.x + threadIdx.x) >> 6;
  if (wid >= N_NODES) return;
  const int lane = threadIdx.x & 63;
  const int e0 = offsets[wid];
  const int e1 = offsets[wid + 1];

  float a0 = 0.f, a1 = 0.f, a2 = 0.f, a3 = 0.f;

  for (int base = e0; base < e1; base += 64) {
    const int avail = e1 - base;
    int2 d = make_int2(0, 0);
    if (lane < avail) d = edata[base + lane];
    const int n = (avail < 64) ? avail : 64;
    int j = 0;
    for (; j + 4 <= n; j += 4) {
      const int   s0 = __shfl(d.x, j, 64),     s1 = __shfl(d.x, j + 1, 64);
      const int   s2 = __shfl(d.x, j + 2, 64), s3 = __shfl(d.x, j + 3, 64);
      const float w0 = __int_as_float(__shfl(d.y, j, 64));
      const float w1 = __int_as_float(__shfl(d.y, j + 1, 64));
      const float w2 = __int_as_float(__shfl(d.y, j + 2, 64));
      const float w3 = __int_as_float(__shfl(d.y, j + 3, 64));
      const ushort4 h0 = *(const ushort4*)(Hb + (size_t)s0 * OUT_CH + lane * 4);
      const ushort4 h1 = *(const ushort4*)(Hb + (size_t)s1 * OUT_CH + lane * 4);
      const ushort4 h2 = *(const ushort4*)(Hb + (size_t)s2 * OUT_CH + lane * 4);
      const ushort4 h3 = *(const ushort4*)(Hb + (size_t)s3 * OUT_CH + lane * 4);
      a0 += w0 * bf2f(h0.x) + w1 * bf2f(h1.x) + w2 * bf2f(h2.x) + w3 * bf2f(h3.x);
      a1 += w0 * bf2f(h0.y) + w1 * bf2f(h1.y) + w2 * bf2f(h2.y) + w3 * bf2f(h3.y);
      a2 += w0 * bf2f(h0.z) + w1 * bf2f(h1.z) + w2 * bf2f(h2.z) + w3 * bf2f(h3.z);
      a3 += w0 * bf2f(h0.w) + w1 * bf2f(h1.w) + w2 * bf2f(h2.w) + w3 * bf2f(h3.w);
    }
    for (; j < n; j++) {
      const int   s = __shfl(d.x, j, 64);
      const float wgt = __int_as_float(__shfl(d.y, j, 64));
      const ushort4 h = *(const ushort4*)(Hb + (size_t)s * OUT_CH + lane * 4);
      a0 += wgt * bf2f(h.x); a1 += wgt * bf2f(h.y);
      a2 += wgt * bf2f(h.z); a3 += wgt * bf2f(h.w);
    }
  }

  const float swv = sw[wid];
  const ushort4 hs = *(const ushort4*)(Hb + (size_t)wid * OUT_CH + lane * 4);
  float4 o;
  o.x = a0 + swv * bf2f(hs.x);
  o.y = a1 + swv * bf2f(hs.y);
  o.z = a2 + swv * bf2f(hs.z);
  o.w = a3 + swv * bf2f(hs.w);
  *(float4*)(OUT + (size_t)wid * OUT_CH + lane * 4) = o;
}

extern "C" void kernel_launch(void* const* d_in, const int* in_sizes, int n_in,
                              void* d_out, int out_size, void* d_ws, size_t ws_size,
                              hipStream_t stream) {
  const float* x   = (const float*)d_in[0];
  const float* W   = (const float*)d_in[1];
  const float* b   = (const float*)d_in[2];
  const int*   src = (const int*)d_in[3];
  const int*   tar = (const int*)d_in[4];
  const float* ew  = (const float*)d_in[5];
  const float* sw  = (const float*)d_in[6];
  float* out = (float*)d_out;

  // ws: Wb 0.5MB | Hb 25.6MB | counts | offsets | cursor | blocksum | edata 6.4MB  (~33MB)
  char* ws = (char*)d_ws;
  size_t o = 0;
  unsigned short* Wb = (unsigned short*)(ws + o);
  o += (size_t)OUT_CH * IN_CH * 2;          o = (o + 255) & ~(size_t)255;
  unsigned short* Hb = (unsigned short*)(ws + o);
  o += (size_t)N_NODES * OUT_CH * 2;        o = (o + 255) & ~(size_t)255;
  int* counts   = (int*)(ws + o); o += (size_t)N_NODES * 4;       o = (o + 255) & ~(size_t)255;
  int* offsets  = (int*)(ws + o); o += (size_t)(N_NODES + 1) * 4; o = (o + 255) & ~(size_t)255;
  int* cursor   = (int*)(ws + o); o += (size_t)N_NODES * 4;       o = (o + 255) & ~(size_t)255;
  int* blocksum = (int*)(ws + o); o += (size_t)NBLK * 4;          o = (o + 255) & ~(size_t)255;
  int2* edata   = (int2*)(ws + o);

  hipMemsetAsync(counts, 0, (size_t)N_NODES * 4, stream);
  prep_hist<<<256 + (N_EDGES + 255) / 256, 256, 0, stream>>>(W, Wb, tar, counts);
  scan_block<<<NBLK, 256, 0, stream>>>(counts, offsets, blocksum);
  scan_sums<<<1, 256, 0, stream>>>(blocksum, offsets);
  finalize_offsets<<<NBLK, 256, 0, stream>>>(offsets, blocksum, cursor);
  fill_csr<<<(N_EDGES + 255) / 256, 256, 0, stream>>>(src, tar, ew, cursor, edata);

  dim3 g1((N_NODES + 63) / 64, OUT_CH / 128);
  gemm_proj<<<g1, 256, 0, stream>>>(x, Wb, b, Hb);

  const long long nthreads = (long long)N_NODES * 64;
  node_agg<<<(int)((nthreads + 255) / 256), 256, 0, stream>>>(Hb, offsets, edata, sw, out);
}

// Round 5
// 236.282 us; speedup vs baseline: 11.7448x; 1.0328x over previous
//
#include <hip/hip_runtime.h>
#include <hip/hip_bf16.h>

#define N_NODES 50000
#define N_EDGES 800000
#define IN_CH 1024
#define OUT_CH 256
#define NBLK 196  // ceil(N_NODES/256)

typedef __attribute__((ext_vector_type(8))) short bf16x8;
typedef __attribute__((ext_vector_type(4))) float f32x4;

__device__ inline unsigned short f2bf(float f) {
  union { float f; unsigned int u; } v; v.f = f;
  unsigned int r = v.u + 0x7fffu + ((v.u >> 16) & 1u);
  return (unsigned short)(r >> 16);
}
__device__ inline float bf2f(unsigned short u) {
  union { unsigned int u; float f; } v; v.u = ((unsigned int)u) << 16;
  return v.f;
}
// pack two f32 -> two bf16 in one u32 (lo = a, hi = b), RNE
__device__ inline unsigned int cvtpk_bf16(float a, float b) {
  unsigned int r;
  asm("v_cvt_pk_bf16_f32 %0, %1, %2" : "=v"(r) : "v"(a), "v"(b));
  return r;
}

// blocks [0,256): convert W fp32 -> bf16; blocks [256,...): histogram of tar
__global__ __launch_bounds__(256) void prep_hist(const float* __restrict__ W,
                                                 unsigned short* __restrict__ Wb,
                                                 const int* __restrict__ tar,
                                                 int* __restrict__ counts) {
  const int b = blockIdx.x, t = threadIdx.x;
  if (b < 256) {
    const int i4 = (b * 256 + t) * 4;
    float4 f = *(const float4*)(W + i4);
    *(ushort4*)(Wb + i4) = make_ushort4(f2bf(f.x), f2bf(f.y), f2bf(f.z), f2bf(f.w));
  } else {
    const int e = (b - 256) * 256 + t;
    if (e < N_EDGES) atomicAdd(&counts[tar[e]], 1);
  }
}

// Hb[m][n] = bf16( sum_k X[m][k]*W[n][k] + b[n] )
// 64x128 tile, BK=32, grid (782,2). 4 waves (2x2), wave tile 32x64.
// Fully-unrolled K loop; A prefetch depth 3 (HBM), B depth 2 (L2), dbuf LDS.
__global__ __launch_bounds__(256, 3) void gemm_proj(
    const float* __restrict__ X, const unsigned short* __restrict__ Wb,
    const float* __restrict__ bias, unsigned short* __restrict__ Hb)
{
  __shared__ unsigned short lds_a[2][64][32];    // 8 KB
  __shared__ unsigned short lds_b[2][128][32];   // 16 KB

  const int tid  = threadIdx.x;
  const int lane = tid & 63;
  const int w    = tid >> 6;
  const int wr   = w >> 1, wc = w & 1;
  const int gm0  = blockIdx.x * 64;
  const int gn0  = blockIdx.y * 128;

  // A staging: 64 rows x 32 fp32; 8 thr/row (float4), rows ar and ar+32
  const int ar = tid >> 3;         // 0..31
  const int ac = (tid & 7) * 4;    // fp32 col
  // B staging: 128 rows x 32 bf16; 4 thr/row (bf16x8), rows br and br+64
  const int br = tid >> 2;         // 0..63
  const int bc = (tid & 3) * 8;    // bf16 col

  const int arow0 = gm0 + ar, arow1 = gm0 + ar + 32;
  const bool aok0 = arow0 < N_NODES, aok1 = arow1 < N_NODES;
  const float* xp0 = X + (size_t)arow0 * IN_CH + ac;
  const float* xp1 = X + (size_t)arow1 * IN_CH + ac;
  const unsigned short* wp0 = Wb + (size_t)(gn0 + br) * IN_CH + bc;
  const unsigned short* wp1 = Wb + (size_t)(gn0 + br + 64) * IN_CH + bc;

  f32x4 acc[2][4];
  #pragma unroll
  for (int i = 0; i < 2; i++)
    #pragma unroll
    for (int j = 0; j < 4; j++) acc[i][j] = (f32x4)0.0f;

  float4 pa[3][2];   // A prefetch, depth 3 (static-indexed under full unroll)
  bf16x8 pb[2][2];   // B prefetch, depth 2

#define LOADA(KS, SL)                                                          \
  {                                                                            \
    const int k0_ = (KS) * 32;                                                 \
    pa[SL][0] = aok0 ? *(const float4*)(xp0 + k0_)                             \
                     : make_float4(0.f, 0.f, 0.f, 0.f);                        \
    pa[SL][1] = aok1 ? *(const float4*)(xp1 + k0_)                             \
                     : make_float4(0.f, 0.f, 0.f, 0.f);                        \
  }
#define LOADB(KS, SL)                                                          \
  {                                                                            \
    const int k0_ = (KS) * 32;                                                 \
    pb[SL][0] = *(const bf16x8*)(wp0 + k0_);                                   \
    pb[SL][1] = *(const bf16x8*)(wp1 + k0_);                                   \
  }
#define WRITER(BUF, SA, SB)                                                    \
  {                                                                            \
    *(uint2*)&lds_a[BUF][ar][ac] =                                             \
        make_uint2(cvtpk_bf16(pa[SA][0].x, pa[SA][0].y),                       \
                   cvtpk_bf16(pa[SA][0].z, pa[SA][0].w));                      \
    *(uint2*)&lds_a[BUF][ar + 32][ac] =                                        \
        make_uint2(cvtpk_bf16(pa[SA][1].x, pa[SA][1].y),                       \
                   cvtpk_bf16(pa[SA][1].z, pa[SA][1].w));                      \
    *(bf16x8*)&lds_b[BUF][br][bc]      = pb[SB][0];                            \
    *(bf16x8*)&lds_b[BUF][br + 64][bc] = pb[SB][1];                            \
  }
#define COMPUTE(BUF)                                                           \
  {                                                                            \
    const int l15_ = lane & 15;                                                \
    const int kb_  = (lane >> 4) * 8;                                          \
    bf16x8 a0 = *(const bf16x8*)&lds_a[BUF][wr * 32 + l15_][kb_];              \
    bf16x8 a1 = *(const bf16x8*)&lds_a[BUF][wr * 32 + 16 + l15_][kb_];         \
    bf16x8 b0 = *(const bf16x8*)&lds_b[BUF][wc * 64 + l15_][kb_];              \
    bf16x8 b1 = *(const bf16x8*)&lds_b[BUF][wc * 64 + 16 + l15_][kb_];         \
    bf16x8 b2 = *(const bf16x8*)&lds_b[BUF][wc * 64 + 32 + l15_][kb_];         \
    bf16x8 b3 = *(const bf16x8*)&lds_b[BUF][wc * 64 + 48 + l15_][kb_];         \
    acc[0][0] = __builtin_amdgcn_mfma_f32_16x16x32_bf16(a0, b0, acc[0][0], 0, 0, 0); \
    acc[0][1] = __builtin_amdgcn_mfma_f32_16x16x32_bf16(a0, b1, acc[0][1], 0, 0, 0); \
    acc[0][2] = __builtin_amdgcn_mfma_f32_16x16x32_bf16(a0, b2, acc[0][2], 0, 0, 0); \
    acc[0][3] = __builtin_amdgcn_mfma_f32_16x16x32_bf16(a0, b3, acc[0][3], 0, 0, 0); \
    acc[1][0] = __builtin_amdgcn_mfma_f32_16x16x32_bf16(a1, b0, acc[1][0], 0, 0, 0); \
    acc[1][1] = __builtin_amdgcn_mfma_f32_16x16x32_bf16(a1, b1, acc[1][1], 0, 0, 0); \
    acc[1][2] = __builtin_amdgcn_mfma_f32_16x16x32_bf16(a1, b2, acc[1][2], 0, 0, 0); \
    acc[1][3] = __builtin_amdgcn_mfma_f32_16x16x32_bf16(a1, b3, acc[1][3], 0, 0, 0); \
  }

  // prologue: A for steps 0,1,2 in flight; B for steps 0,1
  LOADA(0, 0); LOADA(1, 1); LOADA(2, 2);
  LOADB(0, 0); LOADB(1, 1);
  WRITER(0, 0, 0);   // step 0 -> buf0 (waits only on step-0 loads)
  __syncthreads();

  // steady state: at step ks, A(ks+3) and B(ks+2) issued; loads get 2 full
  // compute phases of slack before their WRITER's vmcnt wait.
  #pragma unroll
  for (int ks = 0; ks < 32; ks++) {
    if (ks + 3 < 32) LOADA(ks + 3, (ks + 3) % 3);
    if (ks + 2 < 32) LOADB(ks + 2, ks & 1);
    COMPUTE(ks & 1);
    if (ks + 1 < 32) WRITER((ks + 1) & 1, (ks + 1) % 3, (ks + 1) & 1);
    __syncthreads();
  }
#undef LOADA
#undef LOADB
#undef WRITER
#undef COMPUTE

  // epilogue: C/D layout col = lane&15, row = (lane>>4)*4 + r
  float bj[4];
  #pragma unroll
  for (int j = 0; j < 4; j++)
    bj[j] = bias[gn0 + wc * 64 + j * 16 + (lane & 15)];

  #pragma unroll
  for (int i = 0; i < 2; i++) {
    const int grow_base = gm0 + wr * 32 + i * 16 + ((lane >> 4) << 2);
    #pragma unroll
    for (int r = 0; r < 4; r++) {
      const int grow = grow_base + r;
      if (grow < N_NODES) {
        #pragma unroll
        for (int j = 0; j < 4; j++) {
          const int gcol = gn0 + wc * 64 + j * 16 + (lane & 15);
          Hb[(size_t)grow * OUT_CH + gcol] = f2bf(acc[i][j][r] + bj[j]);
        }
      }
    }
  }
}

// per-block exclusive scan; local-excl to offsets, block total to blocksum
__global__ __launch_bounds__(256) void scan_block(const int* __restrict__ counts,
                                                  int* __restrict__ offsets,
                                                  int* __restrict__ blocksum) {
  __shared__ int wsum[4];
  const int tid = threadIdx.x, lane = tid & 63, wv = tid >> 6;
  const int i = blockIdx.x * 256 + tid;
  const int v = (i < N_NODES) ? counts[i] : 0;
  int s = v;
  #pragma unroll
  for (int off = 1; off < 64; off <<= 1) {
    int t = __shfl_up(s, off, 64);
    if (lane >= off) s += t;
  }
  if (lane == 63) wsum[wv] = s;
  __syncthreads();
  if (tid == 0) {
    int c = 0;
    #pragma unroll
    for (int k = 0; k < 4; k++) { int t = wsum[k]; wsum[k] = c; c += t; }
  }
  __syncthreads();
  const int excl = wsum[wv] + s - v;
  if (i < N_NODES) offsets[i] = excl;
  if (tid == 255) blocksum[blockIdx.x] = excl + v;
}

__global__ __launch_bounds__(256) void scan_sums(int* __restrict__ blocksum,
                                                 int* __restrict__ offsets) {
  __shared__ int wsum[4];
  const int tid = threadIdx.x, lane = tid & 63, wv = tid >> 6;
  const int v = (tid < NBLK) ? blocksum[tid] : 0;
  int s = v;
  #pragma unroll
  for (int off = 1; off < 64; off <<= 1) {
    int t = __shfl_up(s, off, 64);
    if (lane >= off) s += t;
  }
  if (lane == 63) wsum[wv] = s;
  __syncthreads();
  if (tid == 0) {
    int c = 0;
    #pragma unroll
    for (int k = 0; k < 4; k++) { int t = wsum[k]; wsum[k] = c; c += t; }
  }
  __syncthreads();
  const int excl = wsum[wv] + s - v;
  if (tid < NBLK) blocksum[tid] = excl;
  if (tid == 255) offsets[N_NODES] = excl;
}

__global__ __launch_bounds__(256) void finalize_offsets(int* __restrict__ offsets,
                                                        const int* __restrict__ blocksum,
                                                        int* __restrict__ cursor) {
  const int i = blockIdx.x * 256 + threadIdx.x;
  if (i < N_NODES) {
    const int off = offsets[i] + blocksum[i >> 8];
    offsets[i] = off;
    cursor[i] = off;
  }
}

__global__ __launch_bounds__(256) void fill_csr(const int* __restrict__ src,
                                                const int* __restrict__ tar,
                                                const float* __restrict__ ew,
                                                int* __restrict__ cursor,
                                                int2* __restrict__ edata) {
  int e = blockIdx.x * blockDim.x + threadIdx.x;
  if (e >= N_EDGES) return;
  const int t = tar[e];
  const int p = atomicAdd(&cursor[t], 1);
  edata[p] = make_int2(src[e], __float_as_int(ew[e]));
}

// one wave per node: OUT = sw*h_self + sum_e w_e * h_src
__global__ __launch_bounds__(256) void node_agg(
    const unsigned short* __restrict__ Hb, const int* __restrict__ offsets,
    const int2* __restrict__ edata, const float* __restrict__ sw,
    float* __restrict__ OUT)
{
  const int wid = (blockIdx.x * blockDim.x + threadIdx.x) >> 6;
  if (wid >= N_NODES) return;
  const int lane = threadIdx.x & 63;
  const int e0 = offsets[wid];
  const int e1 = offsets[wid + 1];

  float a0 = 0.f, a1 = 0.f, a2 = 0.f, a3 = 0.f;

  for (int base = e0; base < e1; base += 64) {
    const int avail = e1 - base;
    int2 d = make_int2(0, 0);
    if (lane < avail) d = edata[base + lane];
    const int n = (avail < 64) ? avail : 64;
    int j = 0;
    for (; j + 4 <= n; j += 4) {
      const int   s0 = __shfl(d.x, j, 64),     s1 = __shfl(d.x, j + 1, 64);
      const int   s2 = __shfl(d.x, j + 2, 64), s3 = __shfl(d.x, j + 3, 64);
      const float w0 = __int_as_float(__shfl(d.y, j, 64));
      const float w1 = __int_as_float(__shfl(d.y, j + 1, 64));
      const float w2 = __int_as_float(__shfl(d.y, j + 2, 64));
      const float w3 = __int_as_float(__shfl(d.y, j + 3, 64));
      const ushort4 h0 = *(const ushort4*)(Hb + (size_t)s0 * OUT_CH + lane * 4);
      const ushort4 h1 = *(const ushort4*)(Hb + (size_t)s1 * OUT_CH + lane * 4);
      const ushort4 h2 = *(const ushort4*)(Hb + (size_t)s2 * OUT_CH + lane * 4);
      const ushort4 h3 = *(const ushort4*)(Hb + (size_t)s3 * OUT_CH + lane * 4);
      a0 += w0 * bf2f(h0.x) + w1 * bf2f(h1.x) + w2 * bf2f(h2.x) + w3 * bf2f(h3.x);
      a1 += w0 * bf2f(h0.y) + w1 * bf2f(h1.y) + w2 * bf2f(h2.y) + w3 * bf2f(h3.y);
      a2 += w0 * bf2f(h0.z) + w1 * bf2f(h1.z) + w2 * bf2f(h2.z) + w3 * bf2f(h3.z);
      a3 += w0 * bf2f(h0.w) + w1 * bf2f(h1.w) + w2 * bf2f(h2.w) + w3 * bf2f(h3.w);
    }
    for (; j < n; j++) {
      const int   s = __shfl(d.x, j, 64);
      const float wgt = __int_as_float(__shfl(d.y, j, 64));
      const ushort4 h = *(const ushort4*)(Hb + (size_t)s * OUT_CH + lane * 4);
      a0 += wgt * bf2f(h.x); a1 += wgt * bf2f(h.y);
      a2 += wgt * bf2f(h.z); a3 += wgt * bf2f(h.w);
    }
  }

  const float swv = sw[wid];
  const ushort4 hs = *(const ushort4*)(Hb + (size_t)wid * OUT_CH + lane * 4);
  float4 o;
  o.x = a0 + swv * bf2f(hs.x);
  o.y = a1 + swv * bf2f(hs.y);
  o.z = a2 + swv * bf2f(hs.z);
  o.w = a3 + swv * bf2f(hs.w);
  *(float4*)(OUT + (size_t)wid * OUT_CH + lane * 4) = o;
}

extern "C" void kernel_launch(void* const* d_in, const int* in_sizes, int n_in,
                              void* d_out, int out_size, void* d_ws, size_t ws_size,
                              hipStream_t stream) {
  const float* x   = (const float*)d_in[0];
  const float* W   = (const float*)d_in[1];
  const float* b   = (const float*)d_in[2];
  const int*   src = (const int*)d_in[3];
  const int*   tar = (const int*)d_in[4];
  const float* ew  = (const float*)d_in[5];
  const float* sw  = (const float*)d_in[6];
  float* out = (float*)d_out;

  // ws: Wb 0.5MB | Hb 25.6MB | counts | offsets | cursor | blocksum | edata 6.4MB  (~33MB)
  char* ws = (char*)d_ws;
  size_t o = 0;
  unsigned short* Wb = (unsigned short*)(ws + o);
  o += (size_t)OUT_CH * IN_CH * 2;          o = (o + 255) & ~(size_t)255;
  unsigned short* Hb = (unsigned short*)(ws + o);
  o += (size_t)N_NODES * OUT_CH * 2;        o = (o + 255) & ~(size_t)255;
  int* counts   = (int*)(ws + o); o += (size_t)N_NODES * 4;       o = (o + 255) & ~(size_t)255;
  int* offsets  = (int*)(ws + o); o += (size_t)(N_NODES + 1) * 4; o = (o + 255) & ~(size_t)255;
  int* cursor   = (int*)(ws + o); o += (size_t)N_NODES * 4;       o = (o + 255) & ~(size_t)255;
  int* blocksum = (int*)(ws + o); o += (size_t)NBLK * 4;          o = (o + 255) & ~(size_t)255;
  int2* edata   = (int2*)(ws + o);

  hipMemsetAsync(counts, 0, (size_t)N_NODES * 4, stream);
  prep_hist<<<256 + (N_EDGES + 255) / 256, 256, 0, stream>>>(W, Wb, tar, counts);
  scan_block<<<NBLK, 256, 0, stream>>>(counts, offsets, blocksum);
  scan_sums<<<1, 256, 0, stream>>>(blocksum, offsets);
  finalize_offsets<<<NBLK, 256, 0, stream>>>(offsets, blocksum, cursor);
  fill_csr<<<(N_EDGES + 255) / 256, 256, 0, stream>>>(src, tar, ew, cursor, edata);

  dim3 g1((N_NODES + 63) / 64, OUT_CH / 128);
  gemm_proj<<<g1, 256, 0, stream>>>(x, Wb, b, Hb);

  const long long nthreads = (long long)N_NODES * 64;
  node_agg<<<(int)((nthreads + 255) / 256), 256, 0, stream>>>(Hb, offsets, edata, sw, out);
}

// Round 6
// 233.143 us; speedup vs baseline: 11.9029x; 1.0135x over previous
//
#include <hip/hip_runtime.h>
#include <hip/hip_bf16.h>

#define N_NODES 50000
#define N_EDGES 800000
#define IN_CH 1024
#define OUT_CH 256
#define NBLK 196  // ceil(N_NODES/256)

typedef __attribute__((ext_vector_type(8))) short bf16x8;
typedef __attribute__((ext_vector_type(4))) float f32x4;

__device__ inline unsigned short f2bf(float f) {
  union { float f; unsigned int u; } v; v.f = f;
  unsigned int r = v.u + 0x7fffu + ((v.u >> 16) & 1u);
  return (unsigned short)(r >> 16);
}
__device__ inline float bf2f(unsigned short u) {
  union { unsigned int u; float f; } v; v.u = ((unsigned int)u) << 16;
  return v.f;
}
// pack two f32 -> two bf16 in one u32 (lo = a, hi = b), RNE
__device__ inline unsigned int cvtpk_bf16(float a, float b) {
  unsigned int r;
  asm("v_cvt_pk_bf16_f32 %0, %1, %2" : "=v"(r) : "v"(a), "v"(b));
  return r;
}

// Barrier WITHOUT the __syncthreads vmcnt(0) drain: ds-writes must be visible
// (lgkmcnt(0)), but in-flight global loads (register prefetch) stay in flight.
// Compiler's own counted vmcnt waits protect each load's first register use.
__device__ inline void barrier_nodrain() {
  __builtin_amdgcn_sched_barrier(0);
  asm volatile("s_waitcnt lgkmcnt(0)" ::: "memory");
  __builtin_amdgcn_s_barrier();
  __builtin_amdgcn_sched_barrier(0);
}

// blocks [0,256): convert W fp32 -> bf16; blocks [256,...): histogram of tar
__global__ __launch_bounds__(256) void prep_hist(const float* __restrict__ W,
                                                 unsigned short* __restrict__ Wb,
                                                 const int* __restrict__ tar,
                                                 int* __restrict__ counts) {
  const int b = blockIdx.x, t = threadIdx.x;
  if (b < 256) {
    const int i4 = (b * 256 + t) * 4;
    float4 f = *(const float4*)(W + i4);
    *(ushort4*)(Wb + i4) = make_ushort4(f2bf(f.x), f2bf(f.y), f2bf(f.z), f2bf(f.w));
  } else {
    const int e = (b - 256) * 256 + t;
    if (e < N_EDGES) atomicAdd(&counts[tar[e]], 1);
  }
}

// Hb[m][n] = bf16( sum_k X[m][k]*W[n][k] + b[n] )
// 64x128 tile, BK=32, grid (782,2). 4 waves (2x2), wave tile 32x64.
// Fully-unrolled K loop; A prefetch depth 3, B depth 2, dbuf LDS,
// non-draining barrier (loads survive across steps).
__global__ __launch_bounds__(256, 3) void gemm_proj(
    const float* __restrict__ X, const unsigned short* __restrict__ Wb,
    const float* __restrict__ bias, unsigned short* __restrict__ Hb)
{
  __shared__ unsigned short lds_a[2][64][32];    // 8 KB
  __shared__ unsigned short lds_b[2][128][32];   // 16 KB

  const int tid  = threadIdx.x;
  const int lane = tid & 63;
  const int w    = tid >> 6;
  const int wr   = w >> 1, wc = w & 1;
  const int gm0  = blockIdx.x * 64;
  const int gn0  = blockIdx.y * 128;

  const int ar = tid >> 3;         // 0..31
  const int ac = (tid & 7) * 4;    // fp32 col
  const int br = tid >> 2;         // 0..63
  const int bc = (tid & 3) * 8;    // bf16 col

  const int arow0 = gm0 + ar, arow1 = gm0 + ar + 32;
  const bool aok0 = arow0 < N_NODES, aok1 = arow1 < N_NODES;
  const float* xp0 = X + (size_t)arow0 * IN_CH + ac;
  const float* xp1 = X + (size_t)arow1 * IN_CH + ac;
  const unsigned short* wp0 = Wb + (size_t)(gn0 + br) * IN_CH + bc;
  const unsigned short* wp1 = Wb + (size_t)(gn0 + br + 64) * IN_CH + bc;

  f32x4 acc[2][4];
  #pragma unroll
  for (int i = 0; i < 2; i++)
    #pragma unroll
    for (int j = 0; j < 4; j++) acc[i][j] = (f32x4)0.0f;

  float4 pa[3][2];   // A prefetch, depth 3 (static-indexed under full unroll)
  bf16x8 pb[2][2];   // B prefetch, depth 2

#define LOADA(KS, SL)                                                          \
  {                                                                            \
    const int k0_ = (KS) * 32;                                                 \
    pa[SL][0] = aok0 ? *(const float4*)(xp0 + k0_)                             \
                     : make_float4(0.f, 0.f, 0.f, 0.f);                        \
    pa[SL][1] = aok1 ? *(const float4*)(xp1 + k0_)                             \
                     : make_float4(0.f, 0.f, 0.f, 0.f);                        \
  }
#define LOADB(KS, SL)                                                          \
  {                                                                            \
    const int k0_ = (KS) * 32;                                                 \
    pb[SL][0] = *(const bf16x8*)(wp0 + k0_);                                   \
    pb[SL][1] = *(const bf16x8*)(wp1 + k0_);                                   \
  }
#define WRITER(BUF, SA, SB)                                                    \
  {                                                                            \
    *(uint2*)&lds_a[BUF][ar][ac] =                                             \
        make_uint2(cvtpk_bf16(pa[SA][0].x, pa[SA][0].y),                       \
                   cvtpk_bf16(pa[SA][0].z, pa[SA][0].w));                      \
    *(uint2*)&lds_a[BUF][ar + 32][ac] =                                        \
        make_uint2(cvtpk_bf16(pa[SA][1].x, pa[SA][1].y),                       \
                   cvtpk_bf16(pa[SA][1].z, pa[SA][1].w));                      \
    *(bf16x8*)&lds_b[BUF][br][bc]      = pb[SB][0];                            \
    *(bf16x8*)&lds_b[BUF][br + 64][bc] = pb[SB][1];                            \
  }
#define COMPUTE(BUF)                                                           \
  {                                                                            \
    const int l15_ = lane & 15;                                                \
    const int kb_  = (lane >> 4) * 8;                                          \
    bf16x8 a0 = *(const bf16x8*)&lds_a[BUF][wr * 32 + l15_][kb_];              \
    bf16x8 a1 = *(const bf16x8*)&lds_a[BUF][wr * 32 + 16 + l15_][kb_];         \
    bf16x8 b0 = *(const bf16x8*)&lds_b[BUF][wc * 64 + l15_][kb_];              \
    bf16x8 b1 = *(const bf16x8*)&lds_b[BUF][wc * 64 + 16 + l15_][kb_];         \
    bf16x8 b2 = *(const bf16x8*)&lds_b[BUF][wc * 64 + 32 + l15_][kb_];         \
    bf16x8 b3 = *(const bf16x8*)&lds_b[BUF][wc * 64 + 48 + l15_][kb_];         \
    acc[0][0] = __builtin_amdgcn_mfma_f32_16x16x32_bf16(a0, b0, acc[0][0], 0, 0, 0); \
    acc[0][1] = __builtin_amdgcn_mfma_f32_16x16x32_bf16(a0, b1, acc[0][1], 0, 0, 0); \
    acc[0][2] = __builtin_amdgcn_mfma_f32_16x16x32_bf16(a0, b2, acc[0][2], 0, 0, 0); \
    acc[0][3] = __builtin_amdgcn_mfma_f32_16x16x32_bf16(a0, b3, acc[0][3], 0, 0, 0); \
    acc[1][0] = __builtin_amdgcn_mfma_f32_16x16x32_bf16(a1, b0, acc[1][0], 0, 0, 0); \
    acc[1][1] = __builtin_amdgcn_mfma_f32_16x16x32_bf16(a1, b1, acc[1][1], 0, 0, 0); \
    acc[1][2] = __builtin_amdgcn_mfma_f32_16x16x32_bf16(a1, b2, acc[1][2], 0, 0, 0); \
    acc[1][3] = __builtin_amdgcn_mfma_f32_16x16x32_bf16(a1, b3, acc[1][3], 0, 0, 0); \
  }

  // prologue: A for steps 0,1,2 in flight; B for steps 0,1
  LOADA(0, 0); LOADA(1, 1); LOADA(2, 2);
  LOADB(0, 0); LOADB(1, 1);
  WRITER(0, 0, 0);   // waits (counted) only on step-0 loads
  barrier_nodrain();

  #pragma unroll
  for (int ks = 0; ks < 32; ks++) {
    if (ks + 3 < 32) LOADA(ks + 3, (ks + 3) % 3);
    if (ks + 2 < 32) LOADB(ks + 2, ks & 1);
    COMPUTE(ks & 1);
    if (ks + 1 < 32) WRITER((ks + 1) & 1, (ks + 1) % 3, (ks + 1) & 1);
    barrier_nodrain();
  }
#undef LOADA
#undef LOADB
#undef WRITER
#undef COMPUTE

  // epilogue: C/D layout col = lane&15, row = (lane>>4)*4 + r
  float bj[4];
  #pragma unroll
  for (int j = 0; j < 4; j++)
    bj[j] = bias[gn0 + wc * 64 + j * 16 + (lane & 15)];

  #pragma unroll
  for (int i = 0; i < 2; i++) {
    const int grow_base = gm0 + wr * 32 + i * 16 + ((lane >> 4) << 2);
    #pragma unroll
    for (int r = 0; r < 4; r++) {
      const int grow = grow_base + r;
      if (grow < N_NODES) {
        #pragma unroll
        for (int j = 0; j < 4; j++) {
          const int gcol = gn0 + wc * 64 + j * 16 + (lane & 15);
          Hb[(size_t)grow * OUT_CH + gcol] = f2bf(acc[i][j][r] + bj[j]);
        }
      }
    }
  }
}

// per-block exclusive scan; local-excl to offsets, block total to blocksum
__global__ __launch_bounds__(256) void scan_block(const int* __restrict__ counts,
                                                  int* __restrict__ offsets,
                                                  int* __restrict__ blocksum) {
  __shared__ int wsum[4];
  const int tid = threadIdx.x, lane = tid & 63, wv = tid >> 6;
  const int i = blockIdx.x * 256 + tid;
  const int v = (i < N_NODES) ? counts[i] : 0;
  int s = v;
  #pragma unroll
  for (int off = 1; off < 64; off <<= 1) {
    int t = __shfl_up(s, off, 64);
    if (lane >= off) s += t;
  }
  if (lane == 63) wsum[wv] = s;
  __syncthreads();
  if (tid == 0) {
    int c = 0;
    #pragma unroll
    for (int k = 0; k < 4; k++) { int t = wsum[k]; wsum[k] = c; c += t; }
  }
  __syncthreads();
  const int excl = wsum[wv] + s - v;
  if (i < N_NODES) offsets[i] = excl;
  if (tid == 255) blocksum[blockIdx.x] = excl + v;
}

__global__ __launch_bounds__(256) void scan_sums(int* __restrict__ blocksum,
                                                 int* __restrict__ offsets) {
  __shared__ int wsum[4];
  const int tid = threadIdx.x, lane = tid & 63, wv = tid >> 6;
  const int v = (tid < NBLK) ? blocksum[tid] : 0;
  int s = v;
  #pragma unroll
  for (int off = 1; off < 64; off <<= 1) {
    int t = __shfl_up(s, off, 64);
    if (lane >= off) s += t;
  }
  if (lane == 63) wsum[wv] = s;
  __syncthreads();
  if (tid == 0) {
    int c = 0;
    #pragma unroll
    for (int k = 0; k < 4; k++) { int t = wsum[k]; wsum[k] = c; c += t; }
  }
  __syncthreads();
  const int excl = wsum[wv] + s - v;
  if (tid < NBLK) blocksum[tid] = excl;
  if (tid == 255) offsets[N_NODES] = excl;
}

__global__ __launch_bounds__(256) void finalize_offsets(int* __restrict__ offsets,
                                                        const int* __restrict__ blocksum,
                                                        int* __restrict__ cursor) {
  const int i = blockIdx.x * 256 + threadIdx.x;
  if (i < N_NODES) {
    const int off = offsets[i] + blocksum[i >> 8];
    offsets[i] = off;
    cursor[i] = off;
  }
}

__global__ __launch_bounds__(256) void fill_csr(const int* __restrict__ src,
                                                const int* __restrict__ tar,
                                                const float* __restrict__ ew,
                                                int* __restrict__ cursor,
                                                int2* __restrict__ edata) {
  int e = blockIdx.x * blockDim.x + threadIdx.x;
  if (e >= N_EDGES) return;
  const int t = tar[e];
  const int p = atomicAdd(&cursor[t], 1);
  edata[p] = make_int2(src[e], __float_as_int(ew[e]));
}

// one wave per node: OUT = sw*h_self + sum_e w_e * h_src
__global__ __launch_bounds__(256) void node_agg(
    const unsigned short* __restrict__ Hb, const int* __restrict__ offsets,
    const int2* __restrict__ edata, const float* __restrict__ sw,
    float* __restrict__ OUT)
{
  const int wid = (blockIdx.x * blockDim.x + threadIdx.x) >> 6;
  if (wid >= N_NODES) return;
  const int lane = threadIdx.x & 63;
  const int e0 = offsets[wid];
  const int e1 = offsets[wid + 1];

  float a0 = 0.f, a1 = 0.f, a2 = 0.f, a3 = 0.f;

  for (int base = e0; base < e1; base += 64) {
    const int avail = e1 - base;
    int2 d = make_int2(0, 0);
    if (lane < avail) d = edata[base + lane];
    const int n = (avail < 64) ? avail : 64;
    int j = 0;
    for (; j + 4 <= n; j += 4) {
      const int   s0 = __shfl(d.x, j, 64),     s1 = __shfl(d.x, j + 1, 64);
      const int   s2 = __shfl(d.x, j + 2, 64), s3 = __shfl(d.x, j + 3, 64);
      const float w0 = __int_as_float(__shfl(d.y, j, 64));
      const float w1 = __int_as_float(__shfl(d.y, j + 1, 64));
      const float w2 = __int_as_float(__shfl(d.y, j + 2, 64));
      const float w3 = __int_as_float(__shfl(d.y, j + 3, 64));
      const ushort4 h0 = *(const ushort4*)(Hb + (size_t)s0 * OUT_CH + lane * 4);
      const ushort4 h1 = *(const ushort4*)(Hb + (size_t)s1 * OUT_CH + lane * 4);
      const ushort4 h2 = *(const ushort4*)(Hb + (size_t)s2 * OUT_CH + lane * 4);
      const ushort4 h3 = *(const ushort4*)(Hb + (size_t)s3 * OUT_CH + lane * 4);
      a0 += w0 * bf2f(h0.x) + w1 * bf2f(h1.x) + w2 * bf2f(h2.x) + w3 * bf2f(h3.x);
      a1 += w0 * bf2f(h0.y) + w1 * bf2f(h1.y) + w2 * bf2f(h2.y) + w3 * bf2f(h3.y);
      a2 += w0 * bf2f(h0.z) + w1 * bf2f(h1.z) + w2 * bf2f(h2.z) + w3 * bf2f(h3.z);
      a3 += w0 * bf2f(h0.w) + w1 * bf2f(h1.w) + w2 * bf2f(h2.w) + w3 * bf2f(h3.w);
    }
    for (; j < n; j++) {
      const int   s = __shfl(d.x, j, 64);
      const float wgt = __int_as_float(__shfl(d.y, j, 64));
      const ushort4 h = *(const ushort4*)(Hb + (size_t)s * OUT_CH + lane * 4);
      a0 += wgt * bf2f(h.x); a1 += wgt * bf2f(h.y);
      a2 += wgt * bf2f(h.z); a3 += wgt * bf2f(h.w);
    }
  }

  const float swv = sw[wid];
  const ushort4 hs = *(const ushort4*)(Hb + (size_t)wid * OUT_CH + lane * 4);
  float4 o;
  o.x = a0 + swv * bf2f(hs.x);
  o.y = a1 + swv * bf2f(hs.y);
  o.z = a2 + swv * bf2f(hs.z);
  o.w = a3 + swv * bf2f(hs.w);
  *(float4*)(OUT + (size_t)wid * OUT_CH + lane * 4) = o;
}

extern "C" void kernel_launch(void* const* d_in, const int* in_sizes, int n_in,
                              void* d_out, int out_size, void* d_ws, size_t ws_size,
                              hipStream_t stream) {
  const float* x   = (const float*)d_in[0];
  const float* W   = (const float*)d_in[1];
  const float* b   = (const float*)d_in[2];
  const int*   src = (const int*)d_in[3];
  const int*   tar = (const int*)d_in[4];
  const float* ew  = (const float*)d_in[5];
  const float* sw  = (const float*)d_in[6];
  float* out = (float*)d_out;

  // ws: Wb 0.5MB | Hb 25.6MB | counts | offsets | cursor | blocksum | edata 6.4MB  (~33MB)
  char* ws = (char*)d_ws;
  size_t o = 0;
  unsigned short* Wb = (unsigned short*)(ws + o);
  o += (size_t)OUT_CH * IN_CH * 2;          o = (o + 255) & ~(size_t)255;
  unsigned short* Hb = (unsigned short*)(ws + o);
  o += (size_t)N_NODES * OUT_CH * 2;        o = (o + 255) & ~(size_t)255;
  int* counts   = (int*)(ws + o); o += (size_t)N_NODES * 4;       o = (o + 255) & ~(size_t)255;
  int* offsets  = (int*)(ws + o); o += (size_t)(N_NODES + 1) * 4; o = (o + 255) & ~(size_t)255;
  int* cursor   = (int*)(ws + o); o += (size_t)N_NODES * 4;       o = (o + 255) & ~(size_t)255;
  int* blocksum = (int*)(ws + o); o += (size_t)NBLK * 4;          o = (o + 255) & ~(size_t)255;
  int2* edata   = (int2*)(ws + o);

  hipMemsetAsync(counts, 0, (size_t)N_NODES * 4, stream);
  prep_hist<<<256 + (N_EDGES + 255) / 256, 256, 0, stream>>>(W, Wb, tar, counts);
  scan_block<<<NBLK, 256, 0, stream>>>(counts, offsets, blocksum);
  scan_sums<<<1, 256, 0, stream>>>(blocksum, offsets);
  finalize_offsets<<<NBLK, 256, 0, stream>>>(offsets, blocksum, cursor);
  fill_csr<<<(N_EDGES + 255) / 256, 256, 0, stream>>>(src, tar, ew, cursor, edata);

  dim3 g1((N_NODES + 63) / 64, OUT_CH / 128);
  gemm_proj<<<g1, 256, 0, stream>>>(x, Wb, b, Hb);

  const long long nthreads = (long long)N_NODES * 64;
  node_agg<<<(int)((nthreads + 255) / 256), 256, 0, stream>>>(Hb, offsets, edata, sw, out);
}